// Round 5
// baseline (445.594 us; speedup 1.0000x reference)
//
#include <hip/hip_runtime.h>

#define N_NODES 100000
#define N_PAD 100032      // padded to 64-node tiles for MFMA
#define N_EDGES 1600000
#define NUM_RELS 8
#define KDIM 256      // E_DIM * MAX_LEN
#define HD 64
#define RO 512        // NUM_RELS * 64

// CSR-build partition parameters
#define B_SHIFT 6
#define NBUCK 1568        // ceil(100000/64)=1563, padded
#define NBLK_P 128
#define EPB 12500         // 128 * 12500 = 1.6M exactly

typedef __attribute__((ext_vector_type(8))) short bf16x8;
typedef __attribute__((ext_vector_type(4))) float f32x4;

__device__ inline unsigned short f2bf(float f) {
    unsigned u = __float_as_uint(f);
    u += 0x7fff + ((u >> 16) & 1);   // round-to-nearest-even
    return (unsigned short)(u >> 16);
}
__device__ inline float bf2f(unsigned short s) {
    return __uint_as_float(((unsigned)s) << 16);
}
// truncating pack of two f32 -> two bf16 in one u32
__device__ inline unsigned packtrunc(float x, float y) {
    return (__float_as_uint(x) >> 16) | (__float_as_uint(y) & 0xffff0000u);
}

// ---------------- weights (as R3)
__global__ void k_weights(const float* __restrict__ V1, const float* __restrict__ comp1,
                          const float* __restrict__ V2, const float* __restrict__ comp2,
                          const float* __restrict__ sm_w,
                          unsigned short* __restrict__ Wpack1, unsigned short* __restrict__ Wpack2,
                          unsigned short* __restrict__ smPack) {
    int idx = blockIdx.x * 256 + threadIdx.x;
    if (idx < 2 * NUM_RELS * 64 * 64) {
        int l = idx >> 15;
        int r = (idx >> 12) & 7;
        int k = (idx >> 6) & 63;
        int o = idx & 63;
        const float* V = l ? V2 : V1;
        const float* comp = l ? comp2 : comp1;
        float s = 0.f;
#pragma unroll
        for (int b = 0; b < 8; b++) s += comp[r * 8 + b] * V[(b * 64 + k) * 64 + o];
        int ro = r * 64 + o;
        int sstep = k >> 5, q = (k >> 3) & 3, j = k & 7;
        unsigned short* Wp = l ? Wpack2 : Wpack1;
        Wp[(((sstep * 4 + q) * RO) + ro) * 8 + j] = f2bf(s);
    } else {
        int j = idx - 65536;
        if (j < KDIM * HD) {
            int k = j >> 6, o = j & 63;
            int s = k >> 5, q = (k >> 3) & 3, jj = k & 7;
            smPack[(((s * 4 + q) * 64) + o) * 8 + jj] = f2bf(sm_w[o * KDIM + k]);
        }
    }
}

// ---------------- CSR build pass A: per-block LDS histogram over coarse buckets
__launch_bounds__(256)
__global__ void k_pcount(const int* __restrict__ dst, int* __restrict__ cnt) {
    __shared__ int lh[NBUCK];
    int t = threadIdx.x, blk = blockIdx.x;
    for (int b = t; b < NBUCK; b += 256) lh[b] = 0;
    __syncthreads();
    int base = blk * EPB;
    for (int i = t; i < EPB; i += 256) atomicAdd(&lh[dst[base + i] >> B_SHIFT], 1);
    __syncthreads();
    for (int b = t; b < NBUCK; b += 256) cnt[blk * NBUCK + b] = lh[b];
}

// ---------------- pass B1: per-bucket exclusive scan across the 128 blocks
__global__ void k_pscan(const int* __restrict__ cnt, int* __restrict__ boffm, int* __restrict__ btot) {
    __shared__ int s[NBLK_P];
    int b = blockIdx.x, t = threadIdx.x;
    int v = cnt[t * NBUCK + b];
    s[t] = v;
    __syncthreads();
    for (int off = 1; off < NBLK_P; off <<= 1) {
        int u = (t >= off) ? s[t - off] : 0;
        __syncthreads();
        s[t] += u;
        __syncthreads();
    }
    boffm[t * NBUCK + b] = s[t] - v;
    if (t == NBLK_P - 1) btot[b] = s[NBLK_P - 1];
}

// ---------------- pass B2: exclusive scan over bucket totals -> bucket starts
__global__ void k_bscan(const int* __restrict__ btot, int* __restrict__ bstart, int* __restrict__ rowptr) {
    __shared__ int s[2048];
    int t = threadIdx.x;
    int i0 = t, i1 = t + 1024;
    int v0 = (i0 < NBUCK) ? btot[i0] : 0;
    int v1 = (i1 < NBUCK) ? btot[i1] : 0;
    s[i0] = v0; s[i1] = v1;
    __syncthreads();
    for (int off = 1; off < 2048; off <<= 1) {
        int t0 = (i0 >= off) ? s[i0 - off] : 0;
        int t1 = (i1 >= off) ? s[i1 - off] : 0;
        __syncthreads();
        s[i0] += t0; s[i1] += t1;
        __syncthreads();
    }
    if (i0 < NBUCK) bstart[i0] = s[i0] - v0;
    if (i1 < NBUCK) bstart[i1] = s[i1] - v1;
    if (t == 0) rowptr[N_NODES] = N_EDGES;
}

// ---------------- pass C: scatter edges into bucket-contiguous staging (line-dense runs)
__launch_bounds__(256)
__global__ void k_pscatter(const int* __restrict__ src, const int* __restrict__ dst,
                           const int* __restrict__ et, const float* __restrict__ norm,
                           const int* __restrict__ boffm, const int* __restrict__ bstart,
                           int2* __restrict__ staged) {
    __shared__ int ldsoff[NBUCK];
    int t = threadIdx.x, blk = blockIdx.x;
    for (int b = t; b < NBUCK; b += 256) ldsoff[b] = bstart[b] + boffm[blk * NBUCK + b];
    __syncthreads();
    int base = blk * EPB;
    for (int i = t; i < EPB; i += 256) {
        int e = base + i;
        int d = dst[e];
        int bu = d >> B_SHIFT;
        int pos = atomicAdd(&ldsoff[bu], 1);
        int packed = (src[e] * RO + et[e] * 64) | ((d & 63) << 26);
        staged[pos] = make_int2(packed, __float_as_int(norm[e]));
    }
}

// ---------------- pass D: per-bucket LDS hist+scan -> tickets, rowptr, final edata
__launch_bounds__(256)
__global__ void k_finalize(const int2* __restrict__ staged, const int* __restrict__ bstart,
                           const int* __restrict__ btot, int* __restrict__ rowptr,
                           int2* __restrict__ edata) {
    __shared__ int ldeg[64];
    __shared__ int lscan[64];
    int b = blockIdx.x, t = threadIdx.x;
    int base = bstart[b];
    int cnt = btot[b];
    if (t < 64) ldeg[t] = 0;
    __syncthreads();
    int2 held[8];
    int rank[8], dl[8];
    int nh = 0;
    for (int i = t; i < cnt && nh < 8; i += 256) {
        int2 ed = staged[base + i];
        int d = ((unsigned)ed.x) >> 26;
        held[nh] = ed;
        dl[nh] = d;
        rank[nh] = atomicAdd(&ldeg[d], 1);
        nh++;
    }
    __syncthreads();
    if (t < 64) lscan[t] = ldeg[t];
    __syncthreads();
    for (int off = 1; off < 64; off <<= 1) {
        int u = (t < 64 && t >= off) ? lscan[t - off] : 0;
        __syncthreads();
        if (t < 64) lscan[t] += u;
        __syncthreads();
    }
    // lscan = inclusive; node segment start = base + lscan[d] - ldeg[d]
    if (t < 64) {
        int node = (b << B_SHIFT) + t;
        if (node < N_NODES) rowptr[node] = base + lscan[t] - ldeg[t];
    }
    __syncthreads();
    for (int i = 0; i < nh; i++) {
        int d = dl[i];
        int p = base + lscan[d] - ldeg[d] + rank[i];
        edata[p] = make_int2(held[i].x & 0x03FFFFFF, held[i].y);
    }
}

// ---------------- size matcher (MFMA, no LDS)
__launch_bounds__(256)
__global__ void k_sizematch(const int* __restrict__ feat, const float* __restrict__ emb_w,
                            const unsigned short* __restrict__ smPack, const float* __restrict__ sm_b,
                            unsigned short* __restrict__ xb) {
    int t = threadIdx.x;
    int wave = t >> 6, lane = t & 63;
    int q = lane >> 4, c = lane & 15;
    int n0 = blockIdx.x * 64 + wave * 16;
    int node = n0 + c;
    int nclamp = (node < N_NODES) ? node : (N_NODES - 1);
    const int4* fr = (const int4*)(feat + (size_t)nclamp * 8);
    int4 f0 = fr[0], f1 = fr[1];
    int fidx[8] = {f0.x, f0.y, f0.z, f0.w, f1.x, f1.y, f1.z, f1.w};
    f32x4 acc[4];
#pragma unroll
    for (int i = 0; i < 4; i++) acc[i] = (f32x4){0.f, 0.f, 0.f, 0.f};
    const bf16x8* B8 = (const bf16x8*)smPack;
#pragma unroll
    for (int s = 0; s < 8; s++) {
        const float4* ar = (const float4*)(emb_w + (size_t)fidx[s] * 32 + q * 8);
        float4 a0 = ar[0], a1 = ar[1];
        union { unsigned u[4]; bf16x8 v; } A;
        A.u[0] = packtrunc(a0.x, a0.y);
        A.u[1] = packtrunc(a0.z, a0.w);
        A.u[2] = packtrunc(a1.x, a1.y);
        A.u[3] = packtrunc(a1.z, a1.w);
#pragma unroll
        for (int tl = 0; tl < 4; tl++) {
            bf16x8 b = B8[(s * 4 + q) * 64 + tl * 16 + c];
            acc[tl] = __builtin_amdgcn_mfma_f32_16x16x32_bf16(A.v, b, acc[tl], 0, 0, 0);
        }
    }
    int row_base = n0 + q * 4;
    bool full = (n0 + 15 < N_NODES);
#pragma unroll
    for (int tl = 0; tl < 4; tl++) {
        int o = tl * 16 + c;
        float bia = sm_b[o];
#pragma unroll
        for (int r = 0; r < 4; r++) {
            int nd = row_base + r;
            if (full || nd < N_NODES)
                xb[(size_t)nd * 64 + o] = f2bf(acc[tl][r] + bia);
        }
    }
}

// ---------------- transform (MFMA): H[n][ro] = sum_k xb[n][k] * W[k][ro], bf16 out
__launch_bounds__(256)
__global__ void k_transform(const unsigned short* __restrict__ xb,
                            const unsigned short* __restrict__ Wp,
                            unsigned short* __restrict__ H) {
    int t = threadIdx.x;
    int wave = t >> 6, lane = t & 63;
    int q = lane >> 4, c = lane & 15;
    int n0 = blockIdx.x * 64 + wave * 16;
    int ro0 = blockIdx.y * 128;
    f32x4 acc[8];
#pragma unroll
    for (int i = 0; i < 8; i++) acc[i] = (f32x4){0.f, 0.f, 0.f, 0.f};
    const bf16x8* X8 = (const bf16x8*)xb;
    const bf16x8* W8 = (const bf16x8*)Wp;
#pragma unroll
    for (int s = 0; s < 2; s++) {
        bf16x8 a = X8[(size_t)(n0 + c) * 8 + s * 4 + q];
#pragma unroll
        for (int tl = 0; tl < 8; tl++) {
            bf16x8 b = W8[(s * 4 + q) * RO + ro0 + tl * 16 + c];
            acc[tl] = __builtin_amdgcn_mfma_f32_16x16x32_bf16(a, b, acc[tl], 0, 0, 0);
        }
    }
    int row_base = n0 + q * 4;
    bool full = (n0 + 15 < N_NODES);
#pragma unroll
    for (int tl = 0; tl < 8; tl++) {
        int col = ro0 + tl * 16 + c;
#pragma unroll
        for (int r = 0; r < 4; r++) {
            int node = row_base + r;
            if (full || node < N_NODES)
                H[(size_t)node * RO + col] = f2bf(acc[tl][r]);
        }
    }
}

// ---------------- aggregate: one wave per node; 4 edges in flight (lane>>4),
// ushort4 channels per lane (lane&15). mode: 0 = f32 out, 1 = relu + bf16 out
__launch_bounds__(256)
__global__ void k_aggregate(const unsigned short* __restrict__ H, const int* __restrict__ rowptr,
                            const int2* __restrict__ edata,
                            const float* __restrict__ bias, float* __restrict__ outf,
                            unsigned short* __restrict__ outb, int mode) {
    int wave = threadIdx.x >> 6;
    int lane = threadIdx.x & 63;
    int node = blockIdx.x * 4 + wave;
    if (node >= N_NODES) return;
    int j0 = rowptr[node];
    int j1 = rowptr[node + 1];
    int es = lane >> 4;          // edge slot 0..3
    int c4 = (lane & 15) * 4;    // channel base
    float a0 = 0.f, a1 = 0.f, a2 = 0.f, a3 = 0.f;
    for (int j = j0 + es; j < j1; j += 4) {
        int2 ed = edata[j];
        int o = ed.x;
        float nn = __int_as_float(ed.y);
        ushort4 v = *(const ushort4*)(H + o + c4);
        a0 += nn * bf2f(v.x);
        a1 += nn * bf2f(v.y);
        a2 += nn * bf2f(v.z);
        a3 += nn * bf2f(v.w);
    }
    a0 += __shfl_xor(a0, 16); a1 += __shfl_xor(a1, 16);
    a2 += __shfl_xor(a2, 16); a3 += __shfl_xor(a3, 16);
    a0 += __shfl_xor(a0, 32); a1 += __shfl_xor(a1, 32);
    a2 += __shfl_xor(a2, 32); a3 += __shfl_xor(a3, 32);
    if (es == 0) {
        float4 b = *(const float4*)(bias + c4);
        float r0 = a0 + b.x, r1 = a1 + b.y, r2 = a2 + b.z, r3 = a3 + b.w;
        if (mode == 1) {
            r0 = fmaxf(r0, 0.f); r1 = fmaxf(r1, 0.f);
            r2 = fmaxf(r2, 0.f); r3 = fmaxf(r3, 0.f);
            ushort4 pk = make_ushort4(f2bf(r0), f2bf(r1), f2bf(r2), f2bf(r3));
            *(ushort4*)&outb[(size_t)node * 64 + c4] = pk;
        } else {
            *(float4*)&outf[(size_t)node * 64 + c4] = make_float4(r0, r1, r2, r3);
        }
    }
}

extern "C" void kernel_launch(void* const* d_in, const int* in_sizes, int n_in,
                              void* d_out, int out_size, void* d_ws, size_t ws_size,
                              hipStream_t stream) {
    const int*   feat  = (const int*)d_in[0];
    const int*   src   = (const int*)d_in[1];
    const int*   dst   = (const int*)d_in[2];
    const int*   etype = (const int*)d_in[3];
    const float* norm  = (const float*)d_in[4];
    const float* emb_w = (const float*)d_in[5];
    const float* sm_w  = (const float*)d_in[6];
    const float* sm_b  = (const float*)d_in[7];
    const float* V1    = (const float*)d_in[8];
    const float* comp1 = (const float*)d_in[9];
    const float* b1    = (const float*)d_in[10];
    const float* V2    = (const float*)d_in[11];
    const float* comp2 = (const float*)d_in[12];
    const float* b2    = (const float*)d_in[13];
    float* out = (float*)d_out;

    char* p = (char*)d_ws;
    auto alloc = [&](size_t bytes) { void* q = (void*)p; p += (bytes + 255) & ~(size_t)255; return q; };
    unsigned short* xb = (unsigned short*)alloc((size_t)N_PAD * 64 * 2);   // 12.8 MB
    unsigned short* hb = (unsigned short*)alloc((size_t)N_PAD * 64 * 2);   // 12.8 MB
    unsigned short* H  = (unsigned short*)alloc((size_t)N_NODES * RO * 2); // 102.4 MB
    unsigned short* Wpack1 = (unsigned short*)alloc(64 * RO * 2);
    unsigned short* Wpack2 = (unsigned short*)alloc(64 * RO * 2);
    unsigned short* smPack = (unsigned short*)alloc(KDIM * HD * 2);        // 32 KB
    int*   cnt    = (int*)alloc((size_t)NBLK_P * NBUCK * 4);               // 803 KB
    int*   boffm  = (int*)alloc((size_t)NBLK_P * NBUCK * 4);               // 803 KB
    int*   btot   = (int*)alloc((size_t)NBUCK * 4);
    int*   bstart = (int*)alloc((size_t)NBUCK * 4);
    int*   rowptr = (int*)alloc(((size_t)N_NODES + 1) * 4);
    int2*  staged = (int2*)alloc((size_t)N_EDGES * 8);                     // 12.8 MB
    int2*  edata  = (int2*)alloc((size_t)N_EDGES * 8);                     // 12.8 MB

    k_weights<<<320, 256, 0, stream>>>(V1, comp1, V2, comp2, sm_w, Wpack1, Wpack2, smPack);

    k_pcount<<<NBLK_P, 256, 0, stream>>>(dst, cnt);
    k_pscan<<<NBUCK, NBLK_P, 0, stream>>>(cnt, boffm, btot);
    k_bscan<<<1, 1024, 0, stream>>>(btot, bstart, rowptr);
    k_pscatter<<<NBLK_P, 256, 0, stream>>>(src, dst, etype, norm, boffm, bstart, staged);
    k_finalize<<<NBUCK, 256, 0, stream>>>(staged, bstart, btot, rowptr, edata);

    k_sizematch<<<N_PAD / 64, 256, 0, stream>>>(feat, emb_w, smPack, sm_b, xb);

    k_transform<<<dim3(N_PAD / 64, 4), 256, 0, stream>>>(xb, Wpack1, H);
    k_aggregate<<<N_NODES / 4, 256, 0, stream>>>(H, rowptr, edata, b1, nullptr, hb, 1);

    k_transform<<<dim3(N_PAD / 64, 4), 256, 0, stream>>>(hb, Wpack2, H);
    k_aggregate<<<N_NODES / 4, 256, 0, stream>>>(H, rowptr, edata, b2, out, nullptr, 0);
}